// Round 5
// baseline (171.354 us; speedup 1.0000x reference)
//
#include <hip/hip_runtime.h>
#include <math.h>

#define T_SEQ   2048
#define DMODEL  512
#define NHEADS  8
#define DH      64
#define NEG_INF -1.0e9f

typedef __attribute__((ext_vector_type(8))) short short8;
typedef __attribute__((ext_vector_type(4))) float f32x4;
typedef unsigned int u32;
typedef unsigned short u16;

// cheap bf16 pack: round-half-up, error <= 2^-9 rel. No NaNs in this pipeline.
__device__ __forceinline__ u16 f2bf(float f) {
    union { float f; u32 u; } w; w.f = f;
    return (u16)((w.u + 0x8000u) >> 16);
}

// async global->LDS, 16B per lane. LDS dest must be wave-uniform base + lane*16.
__device__ __forceinline__ void async_load16(const u16* g, u16* l) {
    __builtin_amdgcn_global_load_lds(
        (const __attribute__((address_space(1))) u32*)(const void*)g,
        (__attribute__((address_space(3))) u32*)(void*)l, 16, 0, 0);
}

// ---------------------------------------------------------------------------
// fused fp32->bf16 casts (x + 4 weights) + span-loss scalar. 5120 blocks.
// ---------------------------------------------------------------------------
__global__ void cast_all(const float* __restrict__ x,  const float* __restrict__ wq,
                         const float* __restrict__ wk, const float* __restrict__ wv,
                         const float* __restrict__ wo, const float* __restrict__ sp,
                         u16* __restrict__ xb,  u16* __restrict__ wqb,
                         u16* __restrict__ wkb, u16* __restrict__ wvb,
                         u16* __restrict__ wob, float* __restrict__ loss_out)
{
    const int bid = blockIdx.x;
    const float* src; u16* dst; int i;
    if (bid < 4096) { src = x; dst = xb; i = bid * 256 + threadIdx.x; }
    else {
        const int wsel = (bid - 4096) >> 8;
        src = (wsel == 0) ? wq : (wsel == 1) ? wk : (wsel == 2) ? wv : wo;
        dst = (wsel == 0) ? wqb : (wsel == 1) ? wkb : (wsel == 2) ? wvb : wob;
        i = ((bid - 4096) & 255) * 256 + threadIdx.x;
    }
    float4 v = ((const float4*)src)[i];
    ushort4 o;
    o.x = f2bf(v.x); o.y = f2bf(v.y); o.z = f2bf(v.z); o.w = f2bf(v.w);
    ((ushort4*)dst)[i] = o;
    if (bid == 5119 && threadIdx.x == 0) {
        float s = 0.0f;
        for (int h = 0; h < NHEADS; ++h)
            s += fminf(fmaxf(sp[h], 0.0f), 1.0f);
        loss_out[0] = 2e-4f * (s * 0.125f);
    }
}

// ---------------------------------------------------------------------------
// bf16 MFMA GEMM: C[m][n] = sum_k A[m][k]*W[n][k]  (A @ W^T)
// mode by z: z=0/1 -> bf16 (B,H,T,DH) scatter; z=2 -> bf16 (B,H,DH,T) (V^T);
// scatter=0 -> fp32 row-major M x 512.
// ---------------------------------------------------------------------------
__global__ __launch_bounds__(256)
void gemm_bf16(const u16* __restrict__ A,
               const u16* __restrict__ W0, const u16* __restrict__ W1,
               const u16* __restrict__ W2,
               u16* __restrict__ Cb0, u16* __restrict__ Cb1,
               u16* __restrict__ Cb2,
               float* __restrict__ Cf, int scatter)
{
    constexpr int K = 512, BK = 64;
    const u16* W  = (blockIdx.z == 0) ? W0 : (blockIdx.z == 1) ? W1 : W2;
    u16*       Cb = (blockIdx.z == 0) ? Cb0 : (blockIdx.z == 1) ? Cb1 : Cb2;

    __shared__ __align__(16) u16 smem[16384];   // 32 KB: As|Bs, reused by epilogue
    u16* As = smem;
    u16* Bs = smem + 8192;

    const int t    = threadIdx.x;
    const int lane = t & 63;
    const int wave = t >> 6;
    const int wm   = wave >> 1, wn = wave & 1;
    const int m0   = blockIdx.x * 128, n0 = blockIdx.y * 128;

    const int srow = t >> 3;
    const int kb   = (t & 7) ^ (srow & 7);
    const u16* gA = A + (size_t)(m0 + srow) * K + kb * 8;
    const u16* gW = W + (size_t)(n0 + srow) * K + kb * 8;

    const int rA = wm * 64 + (lane & 15);
    const int rB = wn * 64 + (lane & 15);
    const int kq = lane >> 4;
    const int offA0 = rA * BK + ((kq      ^ (rA & 7)) * 8);
    const int offA1 = rA * BK + (((4 + kq) ^ (rA & 7)) * 8);
    const int offB0 = rB * BK + ((kq      ^ (rB & 7)) * 8);
    const int offB1 = rB * BK + (((4 + kq) ^ (rB & 7)) * 8);

    f32x4 acc[4][4];
#pragma unroll
    for (int it = 0; it < 4; ++it)
#pragma unroll
        for (int jt = 0; jt < 4; ++jt) acc[it][jt] = (f32x4)0.0f;

    for (int k0 = 0; k0 < K; k0 += BK) {
        __syncthreads();
#pragma unroll
        for (int i = 0; i < 4; ++i) {
            async_load16(gA + k0 + i * (32 * K), As + t * 8 + i * 2048);
            async_load16(gW + k0 + i * (32 * K), Bs + t * 8 + i * 2048);
        }
        __syncthreads();

        short8 af[4][2], bfr[4][2];
#pragma unroll
        for (int it = 0; it < 4; ++it) {
            af[it][0]  = *(const short8*)(As + offA0 + it * 16 * BK);
            af[it][1]  = *(const short8*)(As + offA1 + it * 16 * BK);
            bfr[it][0] = *(const short8*)(Bs + offB0 + it * 16 * BK);
            bfr[it][1] = *(const short8*)(Bs + offB1 + it * 16 * BK);
        }
#pragma unroll
        for (int it = 0; it < 4; ++it)
#pragma unroll
            for (int jt = 0; jt < 4; ++jt) {
                acc[it][jt] = __builtin_amdgcn_mfma_f32_16x16x32_bf16(
                    af[it][0], bfr[jt][0], acc[it][jt], 0, 0, 0);
                acc[it][jt] = __builtin_amdgcn_mfma_f32_16x16x32_bf16(
                    af[it][1], bfr[jt][1], acc[it][jt], 0, 0, 0);
            }
    }

    const int r0 = (lane >> 4) * 4;
    const int cl = lane & 15;

    if (scatter) {
        const bool vt_mode = (blockIdx.z == 2);
        constexpr int P = 136;
#pragma unroll
        for (int rnd = 0; rnd < 2; ++rnd) {
            __syncthreads();
#pragma unroll
            for (int s = 0; s < 2; ++s) {
                const int it = rnd * 2 + s;
                const int lrow = wm * 32 + s * 16 + r0;
#pragma unroll
                for (int jt = 0; jt < 4; ++jt) {
                    const int cc = wn * 64 + jt * 16 + cl;
#pragma unroll
                    for (int r = 0; r < 4; ++r)
                        smem[(lrow + r) * P + cc] = f2bf(acc[it][jt][r]);
                }
            }
            __syncthreads();
            if (!vt_mode) {
                // (B,H,T,DH): coalesced uint4 rows
                const int lrow2 = t >> 2;
                const int h2    = (t >> 1) & 1;
                const int dhalf = t & 1;
                const int grow  = m0 + (lrow2 >> 5) * 64 + rnd * 32 + (lrow2 & 31);
                const int b     = grow >> 11, tt = grow & 2047;
                const int h     = (n0 >> 6) + h2;
                u16* dst = Cb + ((size_t)((b * NHEADS + h) * T_SEQ + tt)) * DH + dhalf * 32;
                const u16* srcl = smem + lrow2 * P + h2 * 64 + dhalf * 32;
#pragma unroll
                for (int i = 0; i < 4; ++i)
                    ((uint4*)dst)[i] = *(const uint4*)(srcl + i * 8);
            } else {
                // (B,H,DH,T): transpose read-out, 64B contiguous along t
                const int hd   = t >> 1;
                const int run  = t & 1;
                const int h    = (n0 >> 6) + (hd >> 6);
                const int d    = hd & 63;
                const int tb   = m0 + run * 64 + rnd * 32;
                const int b    = tb >> 11;
                u16* dst = Cb + (((size_t)(b * NHEADS + h) * DH + d) << 11) + (tb & 2047);
                union { uint4 v[4]; u16 s[32]; } pk;
#pragma unroll
                for (int i = 0; i < 32; ++i)
                    pk.s[i] = smem[(run * 32 + i) * P + hd];
#pragma unroll
                for (int i = 0; i < 4; ++i)
                    ((uint4*)dst)[i] = pk.v[i];
            }
        }
    } else {
#pragma unroll
        for (int it = 0; it < 4; ++it) {
#pragma unroll
            for (int r = 0; r < 4; ++r) {
                const int row = m0 + wm * 64 + it * 16 + r0 + r;
#pragma unroll
                for (int jt = 0; jt < 4; ++jt) {
                    const int col = n0 + wn * 64 + jt * 16 + cl;
                    Cf[(size_t)row * DMODEL + col] = acc[it][jt][r];
                }
            }
        }
    }
}

// ---------------------------------------------------------------------------
// MFMA windowed flash attention. 256 thr = 4 waves x 16 q (64 q/block).
// Register-prefetch double buffer for K/V (plain loads cross barriers).
// Grid (32, 32): x encodes (b,h) as x=4h+b -> XCD pinning (linear%8 = x%8),
// 4 (b,h) pairs / XCD = 2 MB K+V, fits per-XCD 4 MB L2.
// Q,K in (B,H,T,DH); Vt in (B,H,DH,T); out bf16 (B,T,DMODEL).
// ---------------------------------------------------------------------------
__global__ __launch_bounds__(256)
void attn_mfma(const u16* __restrict__ Q, const u16* __restrict__ K,
               const u16* __restrict__ Vt, const float* __restrict__ span_params,
               u16* __restrict__ out)
{
    __shared__ __align__(16) u16 Ks[64 * 64];      // [j][dh], XOR-swizzled granules
    __shared__ __align__(16) u16 Vs[64 * 64];      // [dh][j], XOR-swizzled granules
    __shared__ __align__(16) u16 Ps[4][16 * 76];   // per-wave P [q][j], pitch 76

    const int tid  = threadIdx.x;
    const int lane = tid & 63;
    const int w    = tid >> 6;
    const int nl   = lane & 15;
    const int quad = lane >> 4;
    const int b    = blockIdx.x & 3;
    const int h    = blockIdx.x >> 2;
    const int bh   = b * NHEADS + h;
    const int i0   = blockIdx.y * 64;
    const int q0   = i0 + w * 16;

    const u16* Qh = Q  + (size_t)bh * (T_SEQ * DH);
    const u16* Kh = K  + (size_t)bh * (T_SEQ * DH);
    const u16* Vh = Vt + (size_t)bh * (DH * T_SEQ);

    float span = span_params[h];
    span = fminf(fmaxf(span, 0.0f), 1.0f);
    const float eff_span = span * 512.0f;
    const int wspan = (int)(eff_span + 1.0f) + 1;

    // Q A-fragments in registers for the whole kernel
    short8 qf0 = *(const short8*)(Qh + (size_t)(q0 + nl) * DH + quad * 8);
    short8 qf1 = *(const short8*)(Qh + (size_t)(q0 + nl) * DH + 32 + quad * 8);

    // staging: thread t covers (row = t>>2, granule pair p = t&3) = 32 B each of K and V
    const int srow = tid >> 2;
    const int p    = tid & 3;
    const int sw0  = ((2 * p)     ^ (srow & 7)) * 8;
    const int sw1  = ((2 * p + 1) ^ (srow & 7)) * 8;
    const u16* gK = Kh + (size_t)srow * DH + p * 16;
    const u16* gV = Vh + (size_t)srow * T_SEQ + p * 16;
    u16* lK = Ks + srow * 64;
    u16* lV = Vs + srow * 64;

    f32x4 o[4];
    float m_r[4], l_r[4];
#pragma unroll
    for (int d = 0; d < 4; ++d) o[d] = (f32x4)0.0f;
#pragma unroll
    for (int r = 0; r < 4; ++r) { m_r[r] = -1.0e30f; l_r[r] = 0.0f; }

    int j_lo = i0 - wspan;
    if (j_lo < 0) j_lo = 0;
    j_lo &= ~63;

    // prologue prefetch (registers)
    uint4 kr0 = *(const uint4*)(gK + (size_t)j_lo * DH);
    uint4 kr1 = *(const uint4*)(gK + (size_t)j_lo * DH + 8);
    uint4 vr0 = *(const uint4*)(gV + j_lo);
    uint4 vr1 = *(const uint4*)(gV + j_lo + 8);

    for (int j0 = j_lo; j0 <= i0; j0 += 64) {
        __syncthreads();                   // prior iter's LDS reads done
        *(uint4*)(lK + sw0) = kr0;
        *(uint4*)(lK + sw1) = kr1;
        *(uint4*)(lV + sw0) = vr0;
        *(uint4*)(lV + sw1) = vr1;
        __syncthreads();                   // tiles visible

        if (j0 < i0) {                     // prefetch next tile into registers
            const int jn = j0 + 64;
            kr0 = *(const uint4*)(gK + (size_t)jn * DH);
            kr1 = *(const uint4*)(gK + (size_t)jn * DH + 8);
            vr0 = *(const uint4*)(gV + jn);
            vr1 = *(const uint4*)(gV + jn + 8);
        }

        // ---- S = Q K^T per 16-wide key tile ----
        f32x4 s[4];
        bool any[4];
#pragma unroll
        for (int n = 0; n < 4; ++n) {
            const int jn = j0 + n * 16;
            any[n] = (jn <= q0 + 15) &&
                     ((float)(q0 - jn - 15) < eff_span + 1.0f);   // some R>0
            s[n] = (f32x4)0.0f;
            if (any[n]) {
                const int row = n * 16 + nl;
                const u16* kp = Ks + row * 64;
                short8 b0 = *(const short8*)(kp + ((quad ^ (row & 7)) * 8));
                short8 b1 = *(const short8*)(kp + (((4 + quad) ^ (row & 7)) * 8));
                s[n] = __builtin_amdgcn_mfma_f32_16x16x32_bf16(qf0, b0, s[n], 0, 0, 0);
                s[n] = __builtin_amdgcn_mfma_f32_16x16x32_bf16(qf1, b1, s[n], 0, 0, 0);
            }
        }

        // ---- mask + row max, 3-way tile classification (wave-uniform) ----
        float tmax[4] = {-1.0e30f, -1.0e30f, -1.0e30f, -1.0e30f};
#pragma unroll
        for (int n = 0; n < 4; ++n) {
            if (!any[n]) continue;
            const int jn = j0 + n * 16;
            const bool causal_b = (jn + 15 > q0);
            const bool span_b   = ((float)(q0 + 15 - jn) > eff_span - 3.0f);
            if (!causal_b && !span_b) {
#pragma unroll
                for (int r = 0; r < 4; ++r) {
                    const float sv = s[n][r] * 0.125f;
                    s[n][r] = sv;
                    tmax[r] = fmaxf(tmax[r], sv);
                }
            } else if (!span_b) {
#pragma unroll
                for (int r = 0; r < 4; ++r) {
                    const int dist = (q0 + quad * 4 + r) - (jn + nl);
                    const float sv = (dist >= 0) ? s[n][r] * 0.125f : NEG_INF;
                    s[n][r] = sv;
                    tmax[r] = fmaxf(tmax[r], sv);
                }
            } else {
#pragma unroll
                for (int r = 0; r < 4; ++r) {
                    const int dist = (q0 + quad * 4 + r) - (jn + nl);
                    float sv = NEG_INF;
                    if (dist >= 0) {
                        float xv = eff_span - (float)dist;
                        float R  = fminf(fmaxf((xv + 1.0f) * 0.25f, 0.0f), 1.0f);
                        if (R > 0.0f)
                            sv = s[n][r] * 0.125f +
                                 ((R < 1.0f) ? __logf(R + 1e-10f) : 0.0f);
                    }
                    s[n][r] = sv;
                    tmax[r] = fmaxf(tmax[r], sv);
                }
            }
        }

        // ---- online softmax state ----
        float alpha[4];
#pragma unroll
        for (int r = 0; r < 4; ++r) {
            float t = tmax[r];
            t = fmaxf(t, __shfl_xor(t, 1));
            t = fmaxf(t, __shfl_xor(t, 2));
            t = fmaxf(t, __shfl_xor(t, 4));
            t = fmaxf(t, __shfl_xor(t, 8));
            const float m_new = fmaxf(m_r[r], t);
            alpha[r] = __expf(m_r[r] - m_new);
            m_r[r] = m_new;
        }

        // ---- P = exp(S - m) -> bf16 LDS ----
        float psum[4] = {0.0f, 0.0f, 0.0f, 0.0f};
#pragma unroll
        for (int n = 0; n < 4; ++n) {
            if (any[n]) {
#pragma unroll
                for (int r = 0; r < 4; ++r) {
                    const float pv = __expf(s[n][r] - m_r[r]);
                    psum[r] += pv;
                    Ps[w][(quad * 4 + r) * 76 + n * 16 + nl] = f2bf(pv);
                }
            } else {
#pragma unroll
                for (int r = 0; r < 4; ++r)
                    Ps[w][(quad * 4 + r) * 76 + n * 16 + nl] = 0;
            }
        }
#pragma unroll
        for (int r = 0; r < 4; ++r) {
            float ps = psum[r];
            ps += __shfl_xor(ps, 1);
            ps += __shfl_xor(ps, 2);
            ps += __shfl_xor(ps, 4);
            ps += __shfl_xor(ps, 8);
            l_r[r] = l_r[r] * alpha[r] + ps;
#pragma unroll
            for (int d = 0; d < 4; ++d) o[d][r] *= alpha[r];
        }

        // ---- O += P V ----
        const bool kf0 = any[0] | any[1];
        const bool kf1 = any[2] | any[3];
        const u16* pb = Ps[w] + nl * 76;
        short8 a0 = *(const short8*)(pb + quad * 8);
        short8 a1 = *(const short8*)(pb + 32 + quad * 8);
#pragma unroll
        for (int d = 0; d < 4; ++d) {
            const int vrow = d * 16 + nl;
            const u16* vp = Vs + vrow * 64;
            if (kf0) {
                short8 vb0 = *(const short8*)(vp + ((quad ^ (vrow & 7)) * 8));
                o[d] = __builtin_amdgcn_mfma_f32_16x16x32_bf16(a0, vb0, o[d], 0, 0, 0);
            }
            if (kf1) {
                short8 vb1 = *(const short8*)(vp + (((4 + quad) ^ (vrow & 7)) * 8));
                o[d] = __builtin_amdgcn_mfma_f32_16x16x32_bf16(a1, vb1, o[d], 0, 0, 0);
            }
        }
    }

    // ---- epilogue ----
#pragma unroll
    for (int r = 0; r < 4; ++r) {
        const int qg = q0 + quad * 4 + r;
        const float inv_l = 1.0f / l_r[r];
        u16* op = out + (size_t)(b * T_SEQ + qg) * DMODEL + h * 64;
#pragma unroll
        for (int d = 0; d < 4; ++d)
            op[d * 16 + nl] = f2bf(o[d][r] * inv_l);
    }
}

extern "C" void kernel_launch(void* const* d_in, const int* in_sizes, int n_in,
                              void* d_out, int out_size, void* d_ws, size_t ws_size,
                              hipStream_t stream)
{
    (void)in_sizes; (void)n_in; (void)out_size; (void)ws_size;
    const float* x  = (const float*)d_in[0];
    const float* wq = (const float*)d_in[1];
    const float* wk = (const float*)d_in[2];
    const float* wv = (const float*)d_in[3];
    const float* wo = (const float*)d_in[4];
    const float* sp = (const float*)d_in[5];
    float* out = (float*)d_out;

    const size_t elems = (size_t)4 * T_SEQ * DMODEL;  // 4,194,304
    u16* xb  = (u16*)d_ws;
    u16* Qb  = xb  + elems;
    u16* Kb  = Qb  + elems;
    u16* Vtb = Kb  + elems;
    u16* Ab  = Vtb + elems;
    u16* wqb = Ab  + elems;
    u16* wkb = wqb + 262144;
    u16* wvb = wkb + 262144;
    u16* wob = wvb + 262144;

    // casts + loss (one launch)
    cast_all<<<5120, 256, 0, stream>>>(x, wq, wk, wv, wo, sp,
                                       xb, wqb, wkb, wvb, wob, out + elems);
    // Q,K,V projections (V written directly transposed)
    gemm_bf16<<<dim3(64, 4, 3), 256, 0, stream>>>(
        xb, wqb, wkb, wvb, Qb, Kb, Vtb, nullptr, 1);
    // MFMA windowed flash attention (64 q / block, reg-prefetch, XCD-pinned)
    attn_mfma<<<dim3(32, 32), 256, 0, stream>>>(Qb, Kb, Vtb, sp, Ab);
    // output projection (fp32 out)
    gemm_bf16<<<dim3(64, 4, 1), 256, 0, stream>>>(
        Ab, wob, wob, wob, nullptr, nullptr, nullptr, out, 0);
}